// Round 1
// baseline (2114.702 us; speedup 1.0000x reference)
//
#include <hip/hip_runtime.h>

#define NROWS 32768      // B*N = 32*1024
#define LLEN  4096       // L = PRED_LEN
#define MHALF 2048       // complex FFT size for real-FFT trick
#define FBINS 2049       // L/2 + 1
#define KSEL  204        // int(2049 * 0.1)
#define NT    256

// One radix-2 Stockham stage: src -> dst, 1024 butterflies, 4 per thread.
// sgn = -pi for forward, +pi for inverse (unnormalized).
__device__ __forceinline__ void fft_stage(const float2* src, float2* dst,
                                          int t, float sgn, int tid)
{
  const int Ns = 1 << t;
  const float cst = sgn / (float)Ns;
#pragma unroll
  for (int q = 0; q < 4; ++q) {
    const int j = tid + NT * q;            // 0..1023
    const float2 a = src[j];
    const float2 b = src[j + MHALF / 2];
    const int r = j & (Ns - 1);
    float sw, cw;
    sincosf(cst * (float)r, &sw, &cw);
    const float btr = fmaf(b.x, cw, -b.y * sw);
    const float bti = fmaf(b.x, sw,  b.y * cw);
    const int d = ((j >> t) << (t + 1)) | r;
    dst[d]      = make_float2(a.x + btr, a.y + bti);
    dst[d + Ns] = make_float2(a.x - btr, a.y - bti);
  }
}

__global__ __launch_bounds__(NT) void seasonal_freq_kernel(
    const float* __restrict__ xin,
    const float* __restrict__ W1,
    const float* __restrict__ b1,
    const float* __restrict__ W2,
    const float* __restrict__ b2,
    float* __restrict__ out)
{
  __shared__ float2 bufA[MHALF];          // 16 KB
  __shared__ float2 bufB[MHALF];          // 16 KB
  __shared__ float  ampsh[FBINS];         // 8.2 KB
  __shared__ unsigned int hist[NT];
  __shared__ unsigned int scanb[NT];
  __shared__ unsigned int eqmask[65];     // 2080 bits >= 2049
  __shared__ float w1s[16], b1s[16], w2s[16];
  __shared__ float b2s;
  __shared__ float2 cNy;                  // Nyquist bin (index 2048)
  __shared__ unsigned int sh_byte;
  __shared__ int sh_need;

  const int tid = threadIdx.x;
  const float* xr  = xin + (size_t)blockIdx.x * LLEN;
  float*       outr = out + (size_t)blockIdx.x * LLEN;

  if (tid < 16) { w1s[tid] = W1[tid]; b1s[tid] = b1[tid]; w2s[tid] = W2[tid]; }
  if (tid == 0) b2s = b2[0];
  if (tid < 65) eqmask[tid] = 0u;

  // ---- load row as packed complex z_m = x[2m] + i*x[2m+1] ----
  const float4* x4 = (const float4*)xr;
#pragma unroll
  for (int q = 0; q < 4; ++q) {
    const int idx = tid + NT * q;         // 0..1023
    const float4 v = x4[idx];
    bufA[2 * idx]     = make_float2(v.x, v.y);
    bufA[2 * idx + 1] = make_float2(v.z, v.w);
  }
  __syncthreads();

  // ---- forward complex FFT size 2048 (sign -) ----
  {
    float2* s = bufA; float2* d = bufB;
#pragma unroll 1
    for (int t = 0; t < 11; ++t) {
      fft_stage(s, d, t, -3.14159265358979323846f, tid);
      __syncthreads();
      float2* tmp = s; s = d; d = tmp;
    }
    // result now in bufB (11 stages: A->B->A->...->B)
  }

  // ---- unpack to rfft bins c_j (j=0..2047 in bufA, Nyquist in cNy) + amp ----
#pragma unroll 1
  for (int j = tid; j < MHALF; j += NT) {
    const float2 z1 = bufB[j];
    const float2 z2 = bufB[(MHALF - j) & (MHALF - 1)];
    const float Er  = 0.5f * (z1.x + z2.x);
    const float Ei  = 0.5f * (z1.y - z2.y);
    const float Or_ = 0.5f * (z1.y + z2.y);
    const float Oi  = -0.5f * (z1.x - z2.x);
    float sw, cw;   // e^{-2*pi*i*j/4096}
    sincosf(-3.14159265358979323846f * (float)j / (float)MHALF, &sw, &cw);
    const float cr = Er + cw * Or_ - sw * Oi;
    const float ci = Ei + cw * Oi + sw * Or_;
    bufA[j] = make_float2(cr, ci);
    ampsh[j] = sqrtf(cr * cr + ci * ci);
  }
  if (tid == 0) {
    const float2 z0 = bufB[0];
    const float crN = z0.x - z0.y;        // c_Nyquist = Re(Z0) - Im(Z0), exactly real
    cNy = make_float2(crN, 0.f);
    ampsh[MHALF] = fabsf(crN);
  }
  __syncthreads();

  // ---- exact top-KSEL threshold via 4-pass radix select on float bits ----
  // (amp >= 0 so the uint bit pattern is order-isomorphic to the value)
  unsigned int prefix = 0u;
  int need = KSEL;
#pragma unroll 1
  for (int p = 0; p < 4; ++p) {
    const int shift = 24 - 8 * p;
    const unsigned int mask = (p == 0) ? 0u : (0xFFFFFFFFu << (shift + 8));
    hist[tid] = 0u;
    __syncthreads();
#pragma unroll 1
    for (int j = tid; j < FBINS; j += NT) {
      const unsigned int bits = __float_as_uint(ampsh[j]);
      if ((bits & mask) == prefix)
        atomicAdd(&hist[(bits >> shift) & 0xFFu], 1u);
    }
    __syncthreads();
    // inclusive suffix sum over hist (Hillis-Steele, 8 steps)
    scanb[tid] = hist[tid];
    __syncthreads();
#pragma unroll 1
    for (int off = 1; off < NT; off <<= 1) {
      const unsigned int v   = scanb[tid];
      const unsigned int add = (tid + off < NT) ? scanb[tid + off] : 0u;
      __syncthreads();
      scanb[tid] = v + add;
      __syncthreads();
    }
    const int sfx   = (int)scanb[tid];          // count with byte >= tid
    const int above = sfx - (int)hist[tid];     // count with byte >  tid
    if (sfx >= need && above < need) {          // exactly one tid satisfies
      sh_byte = (unsigned int)tid;
      sh_need = need - above;
    }
    __syncthreads();
    prefix |= sh_byte << shift;
    need = sh_need;
    __syncthreads();
  }
  const unsigned int T = prefix;   // exact bit pattern of rank-`204` value

  // ---- tie bitmask (values exactly == T); lax.top_k takes lowest indices first ----
#pragma unroll 1
  for (int j = tid; j < FBINS; j += NT)
    if (__float_as_uint(ampsh[j]) == T)
      atomicOr(&eqmask[j >> 5], 1u << (j & 31));
  __syncthreads();

  // ---- MLP on selected amps, rescale spectrum; zero non-selected ----
#pragma unroll 1
  for (int j = tid; j < FBINS; j += NT) {
    const float v = ampsh[j];
    const unsigned int bits = __float_as_uint(v);
    bool sel = bits > T;
    if (bits == T) {
      const int w = j >> 5;
      int rank = 0;
      for (int u = 0; u < w; ++u) rank += __popc(eqmask[u]);
      rank += __popc(eqmask[w] & ((1u << (j & 31)) - 1u));
      sel = (rank < need);
    }
    float cr = 0.f, ci = 0.f;
    if (sel) {
      float e = b2s;
#pragma unroll
      for (int i = 0; i < 16; ++i) {
        const float h = fmaf(v, w1s[i], b1s[i]);
        e = fmaf(fmaxf(h, 0.f), w2s[i], e);
      }
      const float2 c = (j < MHALF) ? bufA[j] : cNy;
      if (v > 0.f) {
        const float sc = e / v;                // e * e^{i*phase} == (e/amp) * c
        cr = sc * c.x; ci = sc * c.y;
      } else {
        cr = e; ci = 0.f;                      // phase(0)=0
      }
    }
    if (j < MHALF) bufA[j] = make_float2(cr, ci);
    else           cNy    = make_float2(cr, ci);
  }
  __syncthreads();

  // ---- Hermitian pack for inverse: Z_j = E_j + i*O_j ----
  // E = (c_j + conj c_{M-j})/2 ; O = e^{+2pi i j/4096} * (c_j - conj c_{M-j})/2
#pragma unroll 1
  for (int j = tid; j < MHALF; j += NT) {
    const float2 c1 = bufA[j];
    const float2 c2 = (j == 0) ? cNy : bufA[MHALF - j];
    const float Er = 0.5f * (c1.x + c2.x);
    const float Ei = 0.5f * (c1.y - c2.y);
    const float Gr = 0.5f * (c1.x - c2.x);
    const float Gi = 0.5f * (c1.y + c2.y);
    float sw, cw;
    sincosf(3.14159265358979323846f * (float)j / (float)MHALF, &sw, &cw);
    const float Or_ = fmaf(cw, Gr, -sw * Gi);
    const float Oi  = fmaf(cw, Gi,  sw * Gr);
    bufB[j] = make_float2(Er - Oi, Ei + Or_);
  }
  __syncthreads();

  // ---- inverse complex FFT size 2048 (sign +), scale 1/2048 at writeout ----
  float2* res;
  {
    float2* s = bufB; float2* d = bufA;
#pragma unroll 1
    for (int t = 0; t < 11; ++t) {
      fft_stage(s, d, t, 3.14159265358979323846f, tid);
      __syncthreads();
      float2* tmp = s; s = d; d = tmp;
    }
    res = s;   // z_m = x[2m] + i*x[2m+1] (unnormalized by 1/M)
  }

  const float inv = 1.0f / (float)MHALF;
  float4* o4 = (float4*)outr;
#pragma unroll
  for (int q = 0; q < 4; ++q) {
    const int idx = tid + NT * q;
    const float2 za = res[2 * idx];
    const float2 zb = res[2 * idx + 1];
    o4[idx] = make_float4(za.x * inv, za.y * inv, zb.x * inv, zb.y * inv);
  }
}

extern "C" void kernel_launch(void* const* d_in, const int* in_sizes, int n_in,
                              void* d_out, int out_size, void* d_ws, size_t ws_size,
                              hipStream_t stream) {
  const float* x  = (const float*)d_in[0];
  const float* W1 = (const float*)d_in[1];
  const float* b1 = (const float*)d_in[2];
  const float* W2 = (const float*)d_in[3];
  const float* b2 = (const float*)d_in[4];
  float* outp = (float*)d_out;
  dim3 grid(NROWS), block(NT);
  hipLaunchKernelGGL(seasonal_freq_kernel, grid, block, 0, stream,
                     x, W1, b1, W2, b2, outp);
}